// Round 5
// baseline (147.886 us; speedup 1.0000x reference)
//
#include <hip/hip_runtime.h>

// x: (B, T+1, T) fp32.  pad = x[:,0,:], sig = x[:,1:,:]
// s[t] = sum_i |sig[i,t]|; w = sigmoid(pad - s)
// out[:,0,:] = w*pad; out[:,1+i,:] = (1-w[i])*sig[i,:]
//
// Two-kernel streaming decomposition:
//  K1 (colsum): each block streams 32 full rows (8KB contiguous per iter);
//     thread t owns columns 4t..4t+3 -> 4 atomicAdds into ws[b][col].
//  K2 (scale): block (b,row-tile) loads its 32 colsums -> w, writes out row-0
//     slice + scales its 32 rows (NT stores). Blocks run in REVERSE order so
//     the re-read consumes K1's L3-resident tail first (268MB vs 256MB L3).

#define TDIM 2048
#define BDIM 16
#define ROWS 32
#define NTHREADS 512

typedef float floatx4 __attribute__((ext_vector_type(4)));

__global__ __launch_bounds__(NTHREADS, 8) void colsum_kernel(const float* __restrict__ x,
                                                             float* __restrict__ ws) {
    const int blk  = blockIdx.x;                  // 0 .. B*(T/ROWS)-1
    const int b    = blk / (TDIM / ROWS);
    const int tile = blk % (TDIM / ROWS);
    const int r0   = tile * ROWS;
    const int t    = threadIdx.x;

    const size_t plane = (size_t)(TDIM + 1) * TDIM;
    const float* sig = x + (size_t)b * plane + TDIM;
    const float* base = sig + (size_t)r0 * TDIM + 4 * t;   // col 4t of row r0

    float a0 = 0.f, a1 = 0.f, a2 = 0.f, a3 = 0.f;
    #pragma unroll 8
    for (int r = 0; r < ROWS; ++r) {              // one full 8KB row per iter
        const floatx4 v = *reinterpret_cast<const floatx4*>(base + (size_t)r * TDIM);
        a0 += fabsf(v.x); a1 += fabsf(v.y); a2 += fabsf(v.z); a3 += fabsf(v.w);
    }

    float* wsb = ws + (size_t)b * TDIM + 4 * t;
    atomicAdd(wsb + 0, a0);
    atomicAdd(wsb + 1, a1);
    atomicAdd(wsb + 2, a2);
    atomicAdd(wsb + 3, a3);
}

__global__ __launch_bounds__(NTHREADS, 8) void scale_kernel(const float* __restrict__ x,
                                                            const float* __restrict__ ws,
                                                            float* __restrict__ out) {
    const int nb   = BDIM * (TDIM / ROWS);
    const int blk  = nb - 1 - blockIdx.x;         // reverse: consume L3 tail first
    const int b    = blk / (TDIM / ROWS);
    const int tile = blk % (TDIM / ROWS);
    const int r0   = tile * ROWS;
    const int t    = threadIdx.x;

    const size_t plane = (size_t)(TDIM + 1) * TDIM;
    const float* xb  = x   + (size_t)b * plane;
    float*       ob  = out + (size_t)b * plane;
    const float* sig = xb + TDIM;

    __shared__ float lds_scale[ROWS];
    if (t < ROWS) {
        const float s = ws[(size_t)b * TDIM + r0 + t];   // colsum of col r0+t
        const float p = xb[r0 + t];                      // pad[r0+t]
        const float w = 1.0f / (1.0f + expf(s - p));     // sigmoid(p - s)
        ob[r0 + t]    = w * p;                           // out row 0 slice
        lds_scale[t]  = 1.0f - w;
    }
    __syncthreads();

    const float* srcb = sig + (size_t)r0 * TDIM;
    float*       dstb = ob + TDIM + (size_t)r0 * TDIM;
    #pragma unroll 4
    for (int r = 0; r < ROWS; ++r) {              // one full row per iter
        floatx4 v = *reinterpret_cast<const floatx4*>(srcb + (size_t)r * TDIM + 4 * t);
        const float sc = lds_scale[r];
        v.x *= sc; v.y *= sc; v.z *= sc; v.w *= sc;
        __builtin_nontemporal_store(v, reinterpret_cast<floatx4*>(dstb + (size_t)r * TDIM + 4 * t));
    }
}

extern "C" void kernel_launch(void* const* d_in, const int* in_sizes, int n_in,
                              void* d_out, int out_size, void* d_ws, size_t ws_size,
                              hipStream_t stream) {
    const float* x   = (const float*)d_in[0];
    float*       out = (float*)d_out;
    float*       ws  = (float*)d_ws;

    // ws holds colsums: B*T floats = 128 KB. Must be zeroed EVERY call
    // (atomics accumulate; harness does not re-poison between replays).
    hipMemsetAsync(ws, 0, (size_t)BDIM * TDIM * sizeof(float), stream);

    const int nblocks = BDIM * (TDIM / ROWS);     // 16 * 64 = 1024
    colsum_kernel<<<nblocks, NTHREADS, 0, stream>>>(x, ws);
    scale_kernel <<<nblocks, NTHREADS, 0, stream>>>(x, ws, out);
}

// Round 6
// 140.142 us; speedup vs baseline: 1.0553x; 1.0553x over previous
//
#include <hip/hip_runtime.h>

// x: (B, T+1, T) fp32.  pad = x[:,0,:], sig = x[:,1:,:]
// s[t] = sum_i |sig[i,t]|; w = sigmoid(pad - s)
// out[:,0,:] = w*pad; out[:,1+i,:] = (1-w[i])*sig[i,:]
//
// Two-kernel, atomic-free, memset-free decomposition:
//  K1 (colsum): block k streams 32 contiguous rows (1KB/wave contiguous);
//     thread t accumulates |.| for columns 4t..4t+3 across its 32 rows and
//     stores a per-block partial colsum vector ws[k][2048] (plain float4
//     store — deterministic, no zeroing, no atomics).
//  K2 (scale): block k sums the 64 partial vectors of its batch at its 32
//     columns (8KB, L2-resident), computes w, writes out row-0 slice, then
//     streams scale+NT-write of its 32 rows. Reverse block order so the
//     re-read consumes K1's L3-resident tail first (input 268MB vs 256MB L3).

#define TDIM 2048
#define BDIM 16
#define ROWS 32          // rows per block
#define NTHREADS 512
#define NBLK (BDIM * (TDIM / ROWS))   // 1024

typedef float floatx4 __attribute__((ext_vector_type(4)));

__global__ __launch_bounds__(NTHREADS, 8) void colsum_kernel(const float* __restrict__ x,
                                                             float* __restrict__ ws) {
    const int k  = blockIdx.x;               // 0..1023
    const int b  = k >> 6;                   // k / 64
    const int r0 = (k & 63) * ROWS;
    const int t  = threadIdx.x;

    const size_t plane = (size_t)(TDIM + 1) * TDIM;
    const float* src = x + (size_t)b * plane + TDIM + (size_t)r0 * TDIM + 4 * t;

    float a0 = 0.f, a1 = 0.f, a2 = 0.f, a3 = 0.f;
    #pragma unroll 8
    for (int r = 0; r < ROWS; ++r) {         // one full 8KB row per iter
        const floatx4 v = *reinterpret_cast<const floatx4*>(src + (size_t)r * TDIM);
        a0 += fabsf(v.x); a1 += fabsf(v.y); a2 += fabsf(v.z); a3 += fabsf(v.w);
    }

    floatx4 p4; p4.x = a0; p4.y = a1; p4.z = a2; p4.w = a3;
    *reinterpret_cast<floatx4*>(ws + (size_t)k * TDIM + 4 * t) = p4;
}

__global__ __launch_bounds__(NTHREADS, 8) void scale_kernel(const float* __restrict__ x,
                                                            const float* __restrict__ ws,
                                                            float* __restrict__ out) {
    const int k  = NBLK - 1 - blockIdx.x;    // reverse: consume L3 tail first
    const int b  = k >> 6;
    const int r0 = (k & 63) * ROWS;
    const int t  = threadIdx.x;

    const size_t plane = (size_t)(TDIM + 1) * TDIM;
    const float* xb  = x   + (size_t)b * plane;
    float*       ob  = out + (size_t)b * plane;
    const float* sig = xb + TDIM;

    // Reduce the 64 per-rowchunk partials for columns r0..r0+31.
    __shared__ float red[16][ROWS];
    __shared__ float lds_scale[ROWS];
    const int c  = t & 31;                   // column within stripe
    const int jg = t >> 5;                   // 0..15, each covers 4 partials
    float s = 0.f;
    #pragma unroll
    for (int j = 0; j < 4; ++j)
        s += ws[(size_t)(b * 64 + jg * 4 + j) * TDIM + r0 + c];
    red[jg][c] = s;
    __syncthreads();

    if (t < ROWS) {
        float tot = 0.f;
        #pragma unroll
        for (int j = 0; j < 16; ++j) tot += red[j][t];
        const float p = xb[r0 + t];                    // pad[r0+t]
        const float w = 1.0f / (1.0f + expf(tot - p)); // sigmoid(p - tot)
        ob[r0 + t]    = w * p;                         // out row 0 slice
        lds_scale[t]  = 1.0f - w;
    }
    __syncthreads();

    // Stream rows r0..r0+31: out[1+r][*] = scale[r] * sig[r][*].
    const float* srcb = sig + (size_t)r0 * TDIM;
    float*       dstb = ob + TDIM + (size_t)r0 * TDIM;
    #pragma unroll 4
    for (int r = 0; r < ROWS; ++r) {
        floatx4 v = *reinterpret_cast<const floatx4*>(srcb + (size_t)r * TDIM + 4 * t);
        const float sc = lds_scale[r];
        v.x *= sc; v.y *= sc; v.z *= sc; v.w *= sc;
        __builtin_nontemporal_store(v, reinterpret_cast<floatx4*>(dstb + (size_t)r * TDIM + 4 * t));
    }
}

extern "C" void kernel_launch(void* const* d_in, const int* in_sizes, int n_in,
                              void* d_out, int out_size, void* d_ws, size_t ws_size,
                              hipStream_t stream) {
    const float* x   = (const float*)d_in[0];
    float*       out = (float*)d_out;
    float*       ws  = (float*)d_ws;   // needs NBLK*TDIM*4 = 8 MB (ws is ~768 MB)

    colsum_kernel<<<NBLK, NTHREADS, 0, stream>>>(x, ws);
    scale_kernel <<<NBLK, NTHREADS, 0, stream>>>(x, ws, out);
}